// Round 2
// baseline (6381.280 us; speedup 1.0000x reference)
//
#include <hip/hip_runtime.h>
#include <cstddef>

// Problem constants
#define TT 512
#define BB 64
#define EE 512
#define N3 1536   // 3*EE

// GRU scan decomposition: 8 batch-groups x 8 batches; 32 blocks/group,
// each block owns 16 e-columns. 256 blocks total, 1 per CU, 512 thr/block.
// Grid=256 + round-robin block->XCD dispatch => group g (blockIdx&7) lives
// entirely on XCD g (32 blocks = 32 CUs = one XCD). h-exchange therefore
// only needs L2 scope (plain stores + sc0 loads); the epoch barrier stays
// agent-scope (IC) so a placement change can only corrupt data (detectable),
// never hang.
#define GRP 8
#define BPG 32
#define BATG 8
#define EPB 16

typedef float v2f __attribute__((ext_vector_type(2)));

// ---------------------------------------------------------------------------
// L2-scope access helpers for same-XCD h exchange:
//   store: plain global_store -> write-through to the XCD's L2 (acked there).
//   load:  sc0 -> bypass L1, read from the shared L2.
// ---------------------------------------------------------------------------
__device__ __forceinline__ float4 load_l2_x4(const float4* p) {
    float4 r;
    asm volatile("global_load_dwordx4 %0, %1, off sc0" : "=v"(r) : "v"(p));
    return r;
}
__device__ __forceinline__ void store_l2(float* p, float v) {
    asm volatile("global_store_dword %0, %1, off" :: "v"(p), "v"(v) : "memory");
}
__device__ __forceinline__ void wait_vm0() {
    asm volatile("s_waitcnt vmcnt(0)" ::: "memory");
}

// Packed fp32 FMA (VOP3P): d = a*b + c, 2 fp32 lanes per instruction.
__device__ __forceinline__ v2f pk_fma(v2f a, v2f b, v2f c) {
    v2f d;
    asm("v_pk_fma_f32 %0, %1, %2, %3" : "=v"(d) : "v"(a), "v"(b), "v"(c));
    return d;
}

// Fast transcendentals: hw-approx rcp/exp; tanh(x) = 1 - 2/(e^2x + 1)
__device__ __forceinline__ float fast_rcp(float x) {
    return __builtin_amdgcn_rcpf(x);
}
__device__ __forceinline__ float fast_sigmoid(float x) {
    return fast_rcp(1.f + __expf(-x));
}
__device__ __forceinline__ float fast_tanh(float x) {
    return 1.f - 2.f * fast_rcp(1.f + __expf(2.f * x));
}

// Butterfly-sum helpers: distances 1,2,4,8 via DPP (VALU-only),
// distance 16 via ds_swizzle.
template <int CTRL>
__device__ __forceinline__ float dpp_add(float x) {
    const int yi = __builtin_amdgcn_update_dpp(
        0, __builtin_bit_cast(int, x), CTRL, 0xF, 0xF, true);
    return x + __builtin_bit_cast(float, yi);
}
__device__ __forceinline__ float swz16_add(float x) {
    const int yi = __builtin_amdgcn_ds_swizzle(__builtin_bit_cast(int, x), 0x401F);
    return x + __builtin_bit_cast(float, yi);
}
__device__ __forceinline__ float bfly_sum32(float x) {
    x = dpp_add<0xB1>(x);    // xor 1
    x = dpp_add<0x4E>(x);    // xor 2
    x = dpp_add<0x141>(x);   // xor 4 (row_half_mirror)
    x = dpp_add<0x140>(x);   // xor 8 (row_mirror)
    x = swz16_add(x);        // xor 16
    return x;
}

// LDS swizzle (16B units): conflict-free for the 2-unit write and the
// U=4kc+q read pattern.
__device__ __forceinline__ int swz(int u) { return u ^ ((u >> 3) & 3); }

// ---------------------------------------------------------------------------
// Embedding gather: xout[i][:] = emb[idx[i]][:], i = t*B+b
// ---------------------------------------------------------------------------
__global__ void embed_k(const int* __restrict__ idx, const float* __restrict__ emb,
                        float* __restrict__ xout) {
    const int i = blockIdx.x;                 // 0..T*B-1
    const int row = idx[i];
    const float4* s = (const float4*)(emb + (size_t)row * EE);
    float4* d = (float4*)(xout + (size_t)i * EE);
    d[threadIdx.x] = s[threadIdx.x];          // 128 threads * float4 = 512 floats
}

// ---------------------------------------------------------------------------
// x_proj GEMM: C[M][N] = A[M][K] * W[N][K]^T + bias[N]
// M=32768, N=1536, K=512. 128x128 tile, 8x8 per thread, fp32.
// Inner product uses v_pk_fma_f32: B-side pairs are natural (contiguous in
// LDS), A-side broadcast via pair duplication. Halves VALU issue count.
// ---------------------------------------------------------------------------
__global__ __launch_bounds__(256)
void gemm_xp(const float* __restrict__ A, const float* __restrict__ W,
             const float* __restrict__ bias, float* __restrict__ C) {
    constexpr int K = EE, N = N3;
    __shared__ float As[16][132];
    __shared__ float Bs[16][132];
    const int tid = threadIdx.x;
    const int tx = tid & 15, ty = tid >> 4;
    const int m0 = blockIdx.y * 128, n0 = blockIdx.x * 128;
    const int r = tid >> 1;            // 0..127
    const int kq = (tid & 1) * 8;      // 0 or 8
    const float* Ap = A + (size_t)(m0 + r) * K + kq;
    const float* Wp = W + (size_t)(n0 + r) * K + kq;

    v2f acc2[8][4];
#pragma unroll
    for (int i = 0; i < 8; ++i)
#pragma unroll
        for (int j = 0; j < 4; ++j) acc2[i][j] = v2f{0.f, 0.f};

    for (int k0 = 0; k0 < K; k0 += 16) {
        float4 a0 = *(const float4*)(Ap + k0);
        float4 a1 = *(const float4*)(Ap + k0 + 4);
        float4 b0 = *(const float4*)(Wp + k0);
        float4 b1 = *(const float4*)(Wp + k0 + 4);
        __syncthreads();
        As[kq+0][r] = a0.x; As[kq+1][r] = a0.y; As[kq+2][r] = a0.z; As[kq+3][r] = a0.w;
        As[kq+4][r] = a1.x; As[kq+5][r] = a1.y; As[kq+6][r] = a1.z; As[kq+7][r] = a1.w;
        Bs[kq+0][r] = b0.x; Bs[kq+1][r] = b0.y; Bs[kq+2][r] = b0.z; Bs[kq+3][r] = b0.w;
        Bs[kq+4][r] = b1.x; Bs[kq+5][r] = b1.y; Bs[kq+6][r] = b1.z; Bs[kq+7][r] = b1.w;
        __syncthreads();
#pragma unroll
        for (int kk = 0; kk < 16; ++kk) {
            float av[8];
            v2f bv2[4];
            *(float4*)&av[0] = *(const float4*)&As[kk][ty*8];
            *(float4*)&av[4] = *(const float4*)&As[kk][ty*8+4];
            float4 vb0 = *(const float4*)&Bs[kk][tx*8];
            float4 vb1 = *(const float4*)&Bs[kk][tx*8+4];
            bv2[0] = v2f{vb0.x, vb0.y}; bv2[1] = v2f{vb0.z, vb0.w};
            bv2[2] = v2f{vb1.x, vb1.y}; bv2[3] = v2f{vb1.z, vb1.w};
#pragma unroll
            for (int i = 0; i < 8; ++i) {
                v2f aa;
                aa[0] = av[i]; aa[1] = av[i];
#pragma unroll
                for (int j = 0; j < 4; ++j)
                    acc2[i][j] = pk_fma(aa, bv2[j], acc2[i][j]);
            }
        }
    }
#pragma unroll
    for (int i = 0; i < 8; ++i) {
        float* Crow = C + (size_t)(m0 + ty*8 + i) * N + n0 + tx*8;
#pragma unroll
        for (int j = 0; j < 4; ++j) {
            float2 o;
            o.x = acc2[i][j].x + bias[n0 + tx*8 + 2*j];
            o.y = acc2[i][j].y + bias[n0 + tx*8 + 2*j + 1];
            *(float2*)(Crow + 2*j) = o;
        }
    }
}

// ---------------------------------------------------------------------------
// GRU recurrence, batch-grouped, 512 threads (8 waves = 2/SIMD).
// Block = (group g = blockIdx&7, slice sl). Group g owns batches [8g,8g+8);
// block owns e in [16*sl, 16*sl+16).
// Thread (kc = tid&31, et2 = (tid>>5)&7, bh = tid>>8):
//   k-chunk [16kc,16kc+16), e in {e0+et2, e0+et2+8}, bi in [4bh, 4bh+4).
// t==0 is special-cased (h(0)=0 => skip staging + dot) so hbuf needs NO
// host-side init and the h data path never depends on memset coherence.
// ---------------------------------------------------------------------------
__global__ __launch_bounds__(512, 2)
void gru_scan(const float* __restrict__ xp,   // [T][B][3E] (includes b_ih)
              const float* __restrict__ Whh,  // [3E][E] this layer
              const float* __restrict__ bhh,  // [3E]   this layer
              const int* __restrict__ lens,   // [B]
              float* __restrict__ y,          // [T][B][E]
              float* __restrict__ hbuf,       // [GRP][2][BATG][EE]
              float* __restrict__ finals,     // [B][E]
              unsigned* __restrict__ ctrl, unsigned ebase)
{
    const int g  = blockIdx.x & 7;         // batch group (== XCD id, see top)
    const int sl = blockIdx.x >> 3;        // e-slice 0..31
    const int e0 = sl * EPB;
    const int tid = threadIdx.x;
    const int kc  = tid & 31;              // k-chunk (16 floats)
    const int et2 = (tid >> 5) & 7;        // e-pair index
    const int bh  = tid >> 8;              // bi-half (0/1)
    const int bq  = bh * 4;                // first group-local bi of my half
    const int b0  = g * BATG;

    // ---- weights: rows (c, e) for e in {e0+et2, e0+et2+8}, k-chunk kc*16 ----
    v2f w2[3][2][8];
#pragma unroll
    for (int c = 0; c < 3; ++c)
#pragma unroll
        for (int ei = 0; ei < 2; ++ei) {
            const int e = e0 + et2 + ei * 8;
            const float* wr = Whh + (size_t)(c * EE + e) * EE + kc * 16;
#pragma unroll
            for (int q = 0; q < 8; ++q) {
                w2[c][ei][q] = v2f{wr[q*2], wr[q*2+1]};
            }
        }
    float bhv[3][2];
#pragma unroll
    for (int c = 0; c < 3; ++c)
#pragma unroll
        for (int ei = 0; ei < 2; ++ei)
            bhv[c][ei] = bhh[c * EE + e0 + et2 + ei * 8];

    // ---- this lane's epilogue assignment (kc<8 lanes are active) ----
    const int oj  = (kc >> 1) & 3;         // group-local batch sub-index
    const int oei = kc & 1;                // e half
    const int oe  = e0 + et2 + oei * 8;    // output e column
    const int obl = bq + oj;               // group-local batch
    const int ob  = b0 + obl;              // global batch
    const int olen = lens[ob];
    const float obh0 = oei ? bhv[0][1] : bhv[0][0];
    const float obh1 = oei ? bhv[1][1] : bhv[1][0];
    const float obh2 = oei ? bhv[2][1] : bhv[2][0];
    float oh = 0.f;                        // running hidden for my (ob, oe)

    float* hA = hbuf + (size_t)g * 2 * BATG * EE;
    float* hB = hA + BATG * EE;
    unsigned* gc = ctrl + g * 32;          // per-group counter, 128B apart

    // stager identity: thread stages 32B (2 units of 16B) of the 16KB slice
    const int sb = tid >> 6;               // batch row 0..7
    const int su = (tid & 63) * 2;         // logical 16B-unit base

    __shared__ float hs[BATG * EE];        // 16KB, unit-swizzled per row

    for (int t = 0; t < TT; ++t) {
        const float* hc = (t & 1) ? hB : hA;
        float* hn = (t & 1) ? hA : hB;

        // ---- stage h slice to LDS (skip at t=0: h(0)=0, dot skipped) ----
        if (t) {
            const float4* gp = (const float4*)(hc + (size_t)sb * EE);
            float4 g0 = load_l2_x4(gp + su);
            float4 g1 = load_l2_x4(gp + su + 1);
            wait_vm0();
            float* wrow = hs + sb * EE;
            *(float4*)(wrow + 4 * swz(su))     = g0;
            *(float4*)(wrow + 4 * swz(su + 1)) = g1;
        }

        // ---- xp loads for my output (kc<8 lanes; 3 scalars) ----
        float oxv0, oxv1, oxv2;
        if (kc < 8) {
            const float* xpb = xp + ((size_t)t * BB + ob) * N3;
            oxv0 = xpb[0 * EE + oe];
            oxv1 = xpb[1 * EE + oe];
            oxv2 = xpb[2 * EE + oe];
        }
        __syncthreads();

        // ---- dot: acc2[c][ei][j] += w2 * h[bq+j][16kc..16kc+16) ----
        v2f acc2[3][2][4];
#pragma unroll
        for (int c = 0; c < 3; ++c)
#pragma unroll
            for (int ei = 0; ei < 2; ++ei)
#pragma unroll
                for (int j = 0; j < 4; ++j) acc2[c][ei][j] = v2f{0.f, 0.f};

        if (t) {
#pragma unroll
            for (int j = 0; j < 4; ++j) {
                const float* hrow = hs + (bq + j) * EE;
#pragma unroll
                for (int q = 0; q < 4; ++q) {
                    const float4 hv = *(const float4*)(hrow + 4 * swz(4 * kc + q));
                    const v2f h2a = v2f{hv.x, hv.y};
                    const v2f h2b = v2f{hv.z, hv.w};
#pragma unroll
                    for (int c = 0; c < 3; ++c)
#pragma unroll
                        for (int ei = 0; ei < 2; ++ei) {
                            acc2[c][ei][j] = pk_fma(w2[c][ei][2*q],   h2a, acc2[c][ei][j]);
                            acc2[c][ei][j] = pk_fma(w2[c][ei][2*q+1], h2b, acc2[c][ei][j]);
                        }
                }
            }
        }
        // NOTE: no __syncthreads() here — the epoch-barrier pair below already
        // orders this step's hs reads before next step's hs writes.

        // ---- collapse pairs + k-reduction (broadcasts to all kc lanes) ----
        float acc[3][2][4];
#pragma unroll
        for (int c = 0; c < 3; ++c)
#pragma unroll
            for (int ei = 0; ei < 2; ++ei)
#pragma unroll
                for (int j = 0; j < 4; ++j)
                    acc[c][ei][j] = bfly_sum32(acc2[c][ei][j].x + acc2[c][ei][j].y);

        // ---- distributed gate: lane kc<8 computes output (oj, oei) ----
        if (kc < 8) {
            float oa[3];
#pragma unroll
            for (int c = 0; c < 3; ++c) {
                const float x0 = oei ? acc[c][1][0] : acc[c][0][0];
                const float x1 = oei ? acc[c][1][1] : acc[c][0][1];
                const float x2 = oei ? acc[c][1][2] : acc[c][0][2];
                const float x3 = oei ? acc[c][1][3] : acc[c][0][3];
                const float y01 = (oj & 1) ? x1 : x0;
                const float y23 = (oj & 1) ? x3 : x2;
                oa[c] = (oj & 2) ? y23 : y01;
            }
            const bool msk = (t < olen);
            const float rg = fast_sigmoid(oxv0 + oa[0] + obh0);
            const float zg = fast_sigmoid(oxv1 + oa[1] + obh1);
            const float ng = fast_tanh(oxv2 + rg * (oa[2] + obh2));
            const float hnew = (1.f - zg) * ng + zg * oh;
            const float hout = msk ? hnew : oh;
            oh = hout;
            store_l2(hn + (size_t)obl * EE + oe, hout);
            y[((size_t)t * BB + ob) * EE + oe] = msk ? hout : 0.f;
            if (t == TT - 1) finals[(size_t)ob * EE + oe] = hout;
        }

        // ---- group barrier: drain stores, then 32-wide monotonic epoch ----
        wait_vm0();
        __syncthreads();
        if (tid == 0) {
            const unsigned tgt = (unsigned)BPG * (ebase + (unsigned)t + 1u);
            __hip_atomic_fetch_add(gc, 1u, __ATOMIC_RELAXED,
                                   __HIP_MEMORY_SCOPE_AGENT);
            while (__hip_atomic_load(gc, __ATOMIC_RELAXED,
                                     __HIP_MEMORY_SCOPE_AGENT) < tgt)
                __builtin_amdgcn_s_sleep(1);
        }
        __syncthreads();
    }
}

// ---------------------------------------------------------------------------
extern "C" void kernel_launch(void* const* d_in, const int* in_sizes, int n_in,
                              void* d_out, int out_size, void* d_ws, size_t ws_size,
                              hipStream_t stream) {
    const int* input_batch  = (const int*)d_in[0];
    const int* lens         = (const int*)d_in[1];
    const float* emb        = (const float*)d_in[2];
    const float* W_ih       = (const float*)d_in[3];
    const float* W_hh       = (const float*)d_in[4];
    const float* b_ih       = (const float*)d_in[5];
    const float* b_hh       = (const float*)d_in[6];
    float* out = (float*)d_out;
    float* ws  = (float*)d_ws;

    // workspace layout (float offsets)
    const size_t XPROJ = 0;                          // [T][B][3E]
    const size_t XBUF  = (size_t)TT * BB * N3;       // x_emb, then ys0
    const size_t HBUF  = XBUF + (size_t)TT * BB * EE;
    const size_t CTRL  = HBUF + (size_t)GRP * 2 * BATG * EE;
    if (ws_size < (CTRL + 1024) * sizeof(float)) return;

    float* xproj = ws + XPROJ;
    float* xbuf  = ws + XBUF;
    float* hbuf  = ws + HBUF;
    unsigned* ctrl = (unsigned*)(ws + CTRL);

    const size_t OUT_YS = 0;                              // [T][B][E]
    const size_t OUT_FIN = (size_t)TT * BB * EE;          // [L][B][E]

    // zero the barrier counters only (hbuf needs no init: t=0 is computed
    // from h=0 in-kernel, and its stores initialize the ping-pong buffers)
    (void)hipMemsetAsync(ctrl, 0, 1024 * sizeof(unsigned), stream);

    // x = emb[input_batch]
    embed_k<<<dim3(TT * BB), dim3(128), 0, stream>>>(input_batch, emb, xbuf);

    // ---- layer 0 ----
    gemm_xp<<<dim3(N3 / 128, (TT * BB) / 128), dim3(256), 0, stream>>>(
        xbuf, W_ih, b_ih, xproj);
    gru_scan<<<dim3(256), dim3(512), 0, stream>>>(
        xproj, W_hh, b_hh, lens,
        xbuf /* ys0 (x_emb is dead now) */, hbuf,
        out + OUT_FIN /* finals layer 0 */, ctrl, 0u);

    // ---- layer 1 ----
    gemm_xp<<<dim3(N3 / 128, (TT * BB) / 128), dim3(256), 0, stream>>>(
        xbuf, W_ih + (size_t)N3 * EE, b_ih + N3, xproj);
    gru_scan<<<dim3(256), dim3(512), 0, stream>>>(
        xproj, W_hh + (size_t)N3 * EE, b_hh + N3, lens,
        out + OUT_YS /* ys1 = output x */, hbuf,
        out + OUT_FIN + (size_t)BB * EE /* finals layer 1 */, ctrl, 512u);
}

// Round 5
// 6297.194 us; speedup vs baseline: 1.0134x; 1.0134x over previous
//
#include <hip/hip_runtime.h>
#include <cstddef>

// Problem constants
#define TT 512
#define BB 64
#define EE 512
#define N3 1536   // 3*EE

// GRU scan decomposition: 8 batch-groups x 8 batches; 32 blocks/group,
// each block owns 16 e-columns. 256 blocks total, 1 per CU, 512 thr/block.
// Grid=256 + round-robin block->XCD dispatch => group g (blockIdx&7) lives
// entirely on XCD g. CONFIRMED empirically (rounds 1-2: L2-scope h exchange
// passed with absmax at the pure-numerics floor). The h exchange runs at L2
// (XCD) scope; the epoch BARRIER stays at agent (IC) scope — the L2-scope
// barrier variant failed 2/2 benches (suspected stale-line spin hang), so
// it is reverted to the proven form.
#define GRP 8
#define BPG 32
#define BATG 8
#define EPB 16

typedef float v2f __attribute__((ext_vector_type(2)));

// ---------------------------------------------------------------------------
// L2-scope access helpers for same-XCD h exchange:
//   store: plain global_store -> write-through to the XCD's L2 (acked there).
//   load:  sc0 -> bypass L1, read from the shared L2.
// ---------------------------------------------------------------------------
__device__ __forceinline__ float4 load_l2_x4(const float4* p) {
    float4 r;
    asm volatile("global_load_dwordx4 %0, %1, off sc0" : "=v"(r) : "v"(p));
    return r;
}
__device__ __forceinline__ void store_l2(float* p, float v) {
    asm volatile("global_store_dword %0, %1, off" :: "v"(p), "v"(v) : "memory");
}
__device__ __forceinline__ void wait_vm0() {
    asm volatile("s_waitcnt vmcnt(0)" ::: "memory");
}
// Wait until only the most-recent VMEM op may remain outstanding: with the
// issue order [h-store, y-store] this guarantees the h-store completed at L2
// while the y-store (HBM, not consumed by peers) drains in the background.
__device__ __forceinline__ void wait_vm1() {
    asm volatile("s_waitcnt vmcnt(1)" ::: "memory");
}

// Packed fp32 FMA (VOP3P): d = a*b + c, 2 fp32 lanes per instruction.
__device__ __forceinline__ v2f pk_fma(v2f a, v2f b, v2f c) {
    v2f d;
    asm("v_pk_fma_f32 %0, %1, %2, %3" : "=v"(d) : "v"(a), "v"(b), "v"(c));
    return d;
}

// Fast transcendentals: hw-approx rcp/exp; tanh(x) = 1 - 2/(e^2x + 1)
__device__ __forceinline__ float fast_rcp(float x) {
    return __builtin_amdgcn_rcpf(x);
}
__device__ __forceinline__ float fast_sigmoid(float x) {
    return fast_rcp(1.f + __expf(-x));
}
__device__ __forceinline__ float fast_tanh(float x) {
    return 1.f - 2.f * fast_rcp(1.f + __expf(2.f * x));
}

// Butterfly-sum helpers: distances 1,2,4,8 via DPP (VALU-only),
// distance 16 via ds_swizzle.
template <int CTRL>
__device__ __forceinline__ float dpp_add(float x) {
    const int yi = __builtin_amdgcn_update_dpp(
        0, __builtin_bit_cast(int, x), CTRL, 0xF, 0xF, true);
    return x + __builtin_bit_cast(float, yi);
}
__device__ __forceinline__ float swz16_add(float x) {
    const int yi = __builtin_amdgcn_ds_swizzle(__builtin_bit_cast(int, x), 0x401F);
    return x + __builtin_bit_cast(float, yi);
}
__device__ __forceinline__ float bfly_sum32(float x) {
    x = dpp_add<0xB1>(x);    // xor 1
    x = dpp_add<0x4E>(x);    // xor 2
    x = dpp_add<0x141>(x);   // xor 4 (row_half_mirror)
    x = dpp_add<0x140>(x);   // xor 8 (row_mirror)
    x = swz16_add(x);        // xor 16
    return x;
}

// LDS swizzle (16B units): conflict-free for the 2-unit write and the
// U=4kc+q read pattern.
__device__ __forceinline__ int swz(int u) { return u ^ ((u >> 3) & 3); }

// ---------------------------------------------------------------------------
// Embedding gather: xout[i][:] = emb[idx[i]][:], i = t*B+b
// ---------------------------------------------------------------------------
__global__ void embed_k(const int* __restrict__ idx, const float* __restrict__ emb,
                        float* __restrict__ xout) {
    const int i = blockIdx.x;                 // 0..T*B-1
    const int row = idx[i];
    const float4* s = (const float4*)(emb + (size_t)row * EE);
    float4* d = (float4*)(xout + (size_t)i * EE);
    d[threadIdx.x] = s[threadIdx.x];          // 128 threads * float4 = 512 floats
}

// ---------------------------------------------------------------------------
// x_proj GEMM: C[M][N] = A[M][K] * W[N][K]^T + bias[N]
// M=32768, N=1536, K=512. 128x128 tile, 8x8 per thread, fp32.
// Inner product uses v_pk_fma_f32 (B-side packed pairs, A broadcast).
// ---------------------------------------------------------------------------
__global__ __launch_bounds__(256)
void gemm_xp(const float* __restrict__ A, const float* __restrict__ W,
             const float* __restrict__ bias, float* __restrict__ C) {
    constexpr int K = EE, N = N3;
    __shared__ float As[16][132];
    __shared__ float Bs[16][132];
    const int tid = threadIdx.x;
    const int tx = tid & 15, ty = tid >> 4;
    const int m0 = blockIdx.y * 128, n0 = blockIdx.x * 128;
    const int r = tid >> 1;            // 0..127
    const int kq = (tid & 1) * 8;      // 0 or 8
    const float* Ap = A + (size_t)(m0 + r) * K + kq;
    const float* Wp = W + (size_t)(n0 + r) * K + kq;

    v2f acc2[8][4];
#pragma unroll
    for (int i = 0; i < 8; ++i)
#pragma unroll
        for (int j = 0; j < 4; ++j) acc2[i][j] = v2f{0.f, 0.f};

    for (int k0 = 0; k0 < K; k0 += 16) {
        float4 a0 = *(const float4*)(Ap + k0);
        float4 a1 = *(const float4*)(Ap + k0 + 4);
        float4 b0 = *(const float4*)(Wp + k0);
        float4 b1 = *(const float4*)(Wp + k0 + 4);
        __syncthreads();
        As[kq+0][r] = a0.x; As[kq+1][r] = a0.y; As[kq+2][r] = a0.z; As[kq+3][r] = a0.w;
        As[kq+4][r] = a1.x; As[kq+5][r] = a1.y; As[kq+6][r] = a1.z; As[kq+7][r] = a1.w;
        Bs[kq+0][r] = b0.x; Bs[kq+1][r] = b0.y; Bs[kq+2][r] = b0.z; Bs[kq+3][r] = b0.w;
        Bs[kq+4][r] = b1.x; Bs[kq+5][r] = b1.y; Bs[kq+6][r] = b1.z; Bs[kq+7][r] = b1.w;
        __syncthreads();
#pragma unroll
        for (int kk = 0; kk < 16; ++kk) {
            float av[8];
            v2f bv2[4];
            *(float4*)&av[0] = *(const float4*)&As[kk][ty*8];
            *(float4*)&av[4] = *(const float4*)&As[kk][ty*8+4];
            float4 vb0 = *(const float4*)&Bs[kk][tx*8];
            float4 vb1 = *(const float4*)&Bs[kk][tx*8+4];
            bv2[0] = v2f{vb0.x, vb0.y}; bv2[1] = v2f{vb0.z, vb0.w};
            bv2[2] = v2f{vb1.x, vb1.y}; bv2[3] = v2f{vb1.z, vb1.w};
#pragma unroll
            for (int i = 0; i < 8; ++i) {
                v2f aa;
                aa[0] = av[i]; aa[1] = av[i];
#pragma unroll
                for (int j = 0; j < 4; ++j)
                    acc2[i][j] = pk_fma(aa, bv2[j], acc2[i][j]);
            }
        }
    }
#pragma unroll
    for (int i = 0; i < 8; ++i) {
        float* Crow = C + (size_t)(m0 + ty*8 + i) * N + n0 + tx*8;
#pragma unroll
        for (int j = 0; j < 4; ++j) {
            float2 o;
            o.x = acc2[i][j].x + bias[n0 + tx*8 + 2*j];
            o.y = acc2[i][j].y + bias[n0 + tx*8 + 2*j + 1];
            *(float2*)(Crow + 2*j) = o;
        }
    }
}

// ---------------------------------------------------------------------------
// GRU recurrence, batch-grouped, 512 threads (8 waves = 2/SIMD).
// Block = (group g = blockIdx&7, slice sl). Group g owns batches [8g,8g+8);
// block owns e in [16*sl, 16*sl+16).
// Thread (kc = tid&31, et2 = (tid>>5)&7, bh = tid>>8):
//   k-chunk [16kc,16kc+16), e in {e0+et2, e0+et2+8}, bi in [4bh, 4bh+4).
// t==0 is special-cased (h(0)=0 => skip staging + dot) so hbuf needs NO
// host-side init. h exchange at L2 scope; barrier at agent (IC) scope.
// ---------------------------------------------------------------------------
__global__ __launch_bounds__(512, 2)
void gru_scan(const float* __restrict__ xp,   // [T][B][3E] (includes b_ih)
              const float* __restrict__ Whh,  // [3E][E] this layer
              const float* __restrict__ bhh,  // [3E]   this layer
              const int* __restrict__ lens,   // [B]
              float* __restrict__ y,          // [T][B][E]
              float* __restrict__ hbuf,       // [GRP][2][BATG][EE]
              float* __restrict__ finals,     // [B][E]
              unsigned* __restrict__ ctrl, unsigned ebase)
{
    const int g  = blockIdx.x & 7;         // batch group (== XCD id, confirmed)
    const int sl = blockIdx.x >> 3;        // e-slice 0..31
    const int e0 = sl * EPB;
    const int tid = threadIdx.x;
    const int kc  = tid & 31;              // k-chunk (16 floats)
    const int et2 = (tid >> 5) & 7;        // e-pair index
    const int bh  = tid >> 8;              // bi-half (0/1)
    const int bq  = bh * 4;                // first group-local bi of my half
    const int b0  = g * BATG;

    // ---- weights: rows (c, e) for e in {e0+et2, e0+et2+8}, k-chunk kc*16 ----
    v2f w2[3][2][8];
#pragma unroll
    for (int c = 0; c < 3; ++c)
#pragma unroll
        for (int ei = 0; ei < 2; ++ei) {
            const int e = e0 + et2 + ei * 8;
            const float* wr = Whh + (size_t)(c * EE + e) * EE + kc * 16;
#pragma unroll
            for (int q = 0; q < 8; ++q) {
                w2[c][ei][q] = v2f{wr[q*2], wr[q*2+1]};
            }
        }
    float bhv[3][2];
#pragma unroll
    for (int c = 0; c < 3; ++c)
#pragma unroll
        for (int ei = 0; ei < 2; ++ei)
            bhv[c][ei] = bhh[c * EE + e0 + et2 + ei * 8];

    // ---- this lane's epilogue assignment (kc<8 lanes are active) ----
    const int oj  = (kc >> 1) & 3;         // group-local batch sub-index
    const int oei = kc & 1;                // e half
    const int oe  = e0 + et2 + oei * 8;    // output e column
    const int obl = bq + oj;               // group-local batch
    const int ob  = b0 + obl;              // global batch
    const int olen = lens[ob];
    const float obh0 = oei ? bhv[0][1] : bhv[0][0];
    const float obh1 = oei ? bhv[1][1] : bhv[1][0];
    const float obh2 = oei ? bhv[2][1] : bhv[2][0];
    float oh = 0.f;                        // running hidden for my (ob, oe)

    float* hA = hbuf + (size_t)g * 2 * BATG * EE;
    float* hB = hA + BATG * EE;
    unsigned* gc = ctrl + g * 32;          // per-group counter, 128B apart

    // stager identity: thread stages 32B (2 units of 16B) of the 16KB slice
    const int sb = tid >> 6;               // batch row 0..7
    const int su = (tid & 63) * 2;         // logical 16B-unit base

    __shared__ float hs[BATG * EE];        // 16KB, unit-swizzled per row

    for (int t = 0; t < TT; ++t) {
        const float* hc = (t & 1) ? hB : hA;
        float* hn = (t & 1) ? hA : hB;

        // ---- stage h slice to LDS (skip at t=0: h(0)=0, dot skipped) ----
        if (t) {
            const float4* gp = (const float4*)(hc + (size_t)sb * EE);
            float4 g0 = load_l2_x4(gp + su);
            float4 g1 = load_l2_x4(gp + su + 1);
            wait_vm0();
            float* wrow = hs + sb * EE;
            *(float4*)(wrow + 4 * swz(su))     = g0;
            *(float4*)(wrow + 4 * swz(su + 1)) = g1;
        }

        // ---- xp loads for my output (kc<8 lanes; 3 scalars) ----
        float oxv0, oxv1, oxv2;
        if (kc < 8) {
            const float* xpb = xp + ((size_t)t * BB + ob) * N3;
            oxv0 = xpb[0 * EE + oe];
            oxv1 = xpb[1 * EE + oe];
            oxv2 = xpb[2 * EE + oe];
        }
        __syncthreads();

        // ---- dot: acc2[c][ei][j] += w2 * h[bq+j][16kc..16kc+16) ----
        v2f acc2[3][2][4];
#pragma unroll
        for (int c = 0; c < 3; ++c)
#pragma unroll
            for (int ei = 0; ei < 2; ++ei)
#pragma unroll
                for (int j = 0; j < 4; ++j) acc2[c][ei][j] = v2f{0.f, 0.f};

        if (t) {
#pragma unroll
            for (int j = 0; j < 4; ++j) {
                const float* hrow = hs + (bq + j) * EE;
#pragma unroll
                for (int q = 0; q < 4; ++q) {
                    const float4 hv = *(const float4*)(hrow + 4 * swz(4 * kc + q));
                    const v2f h2a = v2f{hv.x, hv.y};
                    const v2f h2b = v2f{hv.z, hv.w};
#pragma unroll
                    for (int c = 0; c < 3; ++c)
#pragma unroll
                        for (int ei = 0; ei < 2; ++ei) {
                            acc2[c][ei][j] = pk_fma(w2[c][ei][2*q],   h2a, acc2[c][ei][j]);
                            acc2[c][ei][j] = pk_fma(w2[c][ei][2*q+1], h2b, acc2[c][ei][j]);
                        }
                }
            }
        }
        // NOTE: no __syncthreads() here — the epoch-barrier pair below already
        // orders this step's hs reads before next step's hs writes.

        // ---- collapse pairs + k-reduction (broadcasts to all kc lanes) ----
        float acc[3][2][4];
#pragma unroll
        for (int c = 0; c < 3; ++c)
#pragma unroll
            for (int ei = 0; ei < 2; ++ei)
#pragma unroll
                for (int j = 0; j < 4; ++j)
                    acc[c][ei][j] = bfly_sum32(acc2[c][ei][j].x + acc2[c][ei][j].y);

        // ---- distributed gate: lane kc<8 computes output (oj, oei) ----
        if (kc < 8) {
            float oa[3];
#pragma unroll
            for (int c = 0; c < 3; ++c) {
                const float x0 = oei ? acc[c][1][0] : acc[c][0][0];
                const float x1 = oei ? acc[c][1][1] : acc[c][0][1];
                const float x2 = oei ? acc[c][1][2] : acc[c][0][2];
                const float x3 = oei ? acc[c][1][3] : acc[c][0][3];
                const float y01 = (oj & 1) ? x1 : x0;
                const float y23 = (oj & 1) ? x3 : x2;
                oa[c] = (oj & 2) ? y23 : y01;
            }
            const bool msk = (t < olen);
            const float rg = fast_sigmoid(oxv0 + oa[0] + obh0);
            const float zg = fast_sigmoid(oxv1 + oa[1] + obh1);
            const float ng = fast_tanh(oxv2 + rg * (oa[2] + obh2));
            const float hnew = (1.f - zg) * ng + zg * oh;
            const float hout = msk ? hnew : oh;
            oh = hout;
            // h-store FIRST (peers need it), then background stores.
            store_l2(hn + (size_t)obl * EE + oe, hout);
            y[((size_t)t * BB + ob) * EE + oe] = msk ? hout : 0.f;
            if (t == TT - 1) finals[(size_t)ob * EE + oe] = hout;
        }

        // ---- group barrier: drain h-store only (y drains in background),
        //      then 32-wide monotonic epoch at agent (IC) scope ----
        wait_vm1();
        __syncthreads();
        if (tid == 0) {
            const unsigned tgt = (unsigned)BPG * (ebase + (unsigned)t + 1u);
            __hip_atomic_fetch_add(gc, 1u, __ATOMIC_RELAXED,
                                   __HIP_MEMORY_SCOPE_AGENT);
            while (__hip_atomic_load(gc, __ATOMIC_RELAXED,
                                     __HIP_MEMORY_SCOPE_AGENT) < tgt)
                __builtin_amdgcn_s_sleep(1);
        }
        __syncthreads();
    }
}

// ---------------------------------------------------------------------------
extern "C" void kernel_launch(void* const* d_in, const int* in_sizes, int n_in,
                              void* d_out, int out_size, void* d_ws, size_t ws_size,
                              hipStream_t stream) {
    const int* input_batch  = (const int*)d_in[0];
    const int* lens         = (const int*)d_in[1];
    const float* emb        = (const float*)d_in[2];
    const float* W_ih       = (const float*)d_in[3];
    const float* W_hh       = (const float*)d_in[4];
    const float* b_ih       = (const float*)d_in[5];
    const float* b_hh       = (const float*)d_in[6];
    float* out = (float*)d_out;
    float* ws  = (float*)d_ws;

    // workspace layout (float offsets)
    const size_t XPROJ = 0;                          // [T][B][3E]
    const size_t XBUF  = (size_t)TT * BB * N3;       // x_emb, then ys0
    const size_t HBUF  = XBUF + (size_t)TT * BB * EE;
    const size_t CTRL  = HBUF + (size_t)GRP * 2 * BATG * EE;
    if (ws_size < (CTRL + 1024) * sizeof(float)) return;

    float* xproj = ws + XPROJ;
    float* xbuf  = ws + XBUF;
    float* hbuf  = ws + HBUF;
    unsigned* ctrl = (unsigned*)(ws + CTRL);

    const size_t OUT_YS = 0;                              // [T][B][E]
    const size_t OUT_FIN = (size_t)TT * BB * EE;          // [L][B][E]

    // zero the barrier counters only (hbuf needs no init: t=0 is computed
    // from h=0 in-kernel, and its stores initialize the ping-pong buffers).
    (void)hipMemsetAsync(ctrl, 0, 1024 * sizeof(unsigned), stream);

    // x = emb[input_batch]
    embed_k<<<dim3(TT * BB), dim3(128), 0, stream>>>(input_batch, emb, xbuf);

    // ---- layer 0 ----
    gemm_xp<<<dim3(N3 / 128, (TT * BB) / 128), dim3(256), 0, stream>>>(
        xbuf, W_ih, b_ih, xproj);
    gru_scan<<<dim3(256), dim3(512), 0, stream>>>(
        xproj, W_hh, b_hh, lens,
        xbuf /* ys0 (x_emb is dead now) */, hbuf,
        out + OUT_FIN /* finals layer 0 */, ctrl, 0u);

    // ---- layer 1 ----
    gemm_xp<<<dim3(N3 / 128, (TT * BB) / 128), dim3(256), 0, stream>>>(
        xbuf, W_ih + (size_t)N3 * EE, b_ih + N3, xproj);
    gru_scan<<<dim3(256), dim3(512), 0, stream>>>(
        xproj, W_hh + (size_t)N3 * EE, b_hh + N3, lens,
        out + OUT_YS /* ys1 = output x */, hbuf,
        out + OUT_FIN + (size_t)BB * EE /* finals layer 1 */, ctrl, 512u);
}